// Round 5
// baseline (476.758 us; speedup 1.0000x reference)
//
#include <hip/hip_runtime.h>
#include <cstdint>
#include <cstddef>

#define HDIM  128
#define NCLS  5
#define NLEAF 65536

typedef unsigned short ushort_t;
typedef __attribute__((ext_vector_type(8))) short short8v;   // 8 bf16 (4 VGPRs)
typedef __attribute__((ext_vector_type(4))) float f32x4;     // MFMA accumulator

__device__ __forceinline__ float sigf(float x) { return 1.0f / (1.0f + __expf(-x)); }

__device__ __forceinline__ unsigned short bf16_rne(float x) {
    unsigned u = __float_as_uint(x);
    u += 0x7FFFu + ((u >> 16) & 1u);
    return (unsigned short)(u >> 16);
}
__device__ __forceinline__ float bf16_f32(unsigned short h) {
    return __uint_as_float(((unsigned)h) << 16);
}

// direct-to-LDS 16B copy: lds dest = wave-uniform base (+lane*16 implicit),
// global src per-lane.
__device__ __forceinline__ void glds16(const ushort_t* g, ushort_t* l) {
    __builtin_amdgcn_global_load_lds((const __attribute__((address_space(1))) void*)g,
                                     (__attribute__((address_space(3))) void*)l,
                                     16, 0, 0);
}

// ---------------------------------------------------------------------------
// Level weight table W4L: [cb 8][cc 16][slot 4][lane 64][e 8] bf16-bits.
//   slot 0..2 = Ui/Uo/Uu (cc 0-7 hi over k=cc*32.., cc 8-15 lo)
//   slot 3    = f-gates packed: cc 0-3 f1-hi, 4-7 f2-hi, 8-11 f1-lo, 12-15 f2-lo
// Block cb's slab = contiguous 64 KB.
// ---------------------------------------------------------------------------
__global__ __launch_bounds__(256)
void prep_level_w4(const float* __restrict__ Ui, const float* __restrict__ Uo,
                   const float* __restrict__ Uu, const float* __restrict__ Uf1,
                   const float* __restrict__ Uf2, ushort_t* __restrict__ W4)
{
    int idx = blockIdx.x * 256 + threadIdx.x;          // 262144
    if (idx >= 262144) return;
    int e    = idx & 7;
    int lane = (idx >> 3) & 63;
    int slot = (idx >> 9) & 3;
    int cc   = (idx >> 11) & 15;
    int cb   = idx >> 15;
    int j    = cb * 16 + (lane & 15);
    int kq   = (lane >> 4) * 8 + e;                    // [0,32)
    float x; int band;
    if (slot < 3) {
        const float* W = (slot == 0) ? Ui : (slot == 1) ? Uo : Uu;
        band = cc >> 3;
        int k = (cc & 7) * 32 + kq;                    // [0,256)
        x = W[k * 128 + j];
    } else {
        band = (cc >> 3) & 1;
        int cm = cc & 7;
        const float* W = (cm < 4) ? Uf1 : Uf2;
        int k = (cm & 3) * 32 + kq;                    // [0,128)
        x = W[k * 128 + j];
    }
    unsigned short h = bf16_rne(x);
    if (band) h = bf16_rne(x - bf16_f32(h));
    W4[idx] = h;
}

// Leaf table W4F: [cb 8][cc 8][slot 3][lane][e]; cc 0-3 hi, 4-7 lo. 24 KB/slab.
__global__ __launch_bounds__(256)
void prep_leaf_w4(const float* __restrict__ Wi, const float* __restrict__ Wo,
                  const float* __restrict__ Wu, ushort_t* __restrict__ W4)
{
    int idx = blockIdx.x * 256 + threadIdx.x;          // 98304
    if (idx >= 98304) return;
    int e    = idx & 7;
    int lane = (idx >> 3) & 63;
    int rest = idx >> 9;
    int slot = rest % 3;
    int cc   = (rest / 3) & 7;
    int cb   = rest / 24;
    int j    = cb * 16 + (lane & 15);
    int kq   = (lane >> 4) * 8 + e;
    int band = cc >> 2;
    int k    = (cc & 3) * 32 + kq;                     // [0,128)
    const float* W = (slot == 0) ? Wi : (slot == 1) ? Wo : Wu;
    float x = W[k * 128 + j];
    unsigned short h = bf16_rne(x);
    if (band) h = bf16_rne(x - bf16_f32(h));
    W4[idx] = h;
}

// ---------------------------------------------------------------------------
// E2 gather: E2[row][hi128|lo128] = hi/lo split of emb[words[row]]
// ---------------------------------------------------------------------------
__global__ __launch_bounds__(256)
void e2_gather(const int* __restrict__ words, const float* __restrict__ emb,
               ushort_t* __restrict__ E2)
{
    int idx = blockIdx.x * 256 + threadIdx.x;          // 65536*128
    int row = idx >> 7, j = idx & 127;
    int w = words[row];
    float x = emb[(size_t)w * 128 + j];
    unsigned short hi = bf16_rne(x);
    unsigned short lo = bf16_rne(x - bf16_f32(hi));
    E2[(size_t)row * 256 + j]       = hi;
    E2[(size_t)row * 256 + 128 + j] = lo;
}

// ---------------------------------------------------------------------------
// Persistent-B level kernel. grid (R, 8): blockIdx.y = cb (16-col gate slice).
// 512 thr = 8 waves; B slab (64 KB) staged once to LDS; waves then free-run
// over T tiles of 32 rows each (no further barriers).
// ---------------------------------------------------------------------------
template<int T>
__global__ __launch_bounds__(512, 4)
void level_gp(const ushort_t* __restrict__ H2in, const float* __restrict__ Cin,
              const ushort_t* __restrict__ W4,
              const float* __restrict__ bUi, const float* __restrict__ bUo,
              const float* __restrict__ bUu, const float* __restrict__ bf1,
              const float* __restrict__ bf2,
              ushort_t* __restrict__ H2out, float* __restrict__ Cout)
{
    __shared__ ushort_t Bl[32768];                     // 64 KB
    const int tid = threadIdx.x, lane = tid & 63, wid = tid >> 6;
    const int l15 = lane & 15, l4 = lane >> 4;
    const int cb = blockIdx.y;
    const ushort_t* slab = W4 + (size_t)cb * 32768;

#pragma unroll
    for (int r = 0; r < 8; ++r)
        glds16(slab + r * 4096 + wid * 512 + lane * 8, Bl + r * 4096 + wid * 512);
    asm volatile("s_waitcnt vmcnt(0)" ::: "memory");
    __syncthreads();

    const int j = cb * 16 + l15;
    const float bi_ = bUi[j], bo_ = bUo[j], bu_ = bUu[j], b1_ = bf1[j], b2_ = bf2[j];
    const int rb = blockIdx.x * (256 * T);

#pragma unroll 1
    for (int t = 0; t < T; ++t) {
        const int row0 = rb + (wid * T + t) * 32;
        const ushort_t* a0 = H2in + (size_t)(2 * (row0 + l15)) * 256;       // 1KB parent line
        const ushort_t* a1 = H2in + (size_t)(2 * (row0 + 16 + l15)) * 256;

        f32x4 acc[2][5];
#pragma unroll
        for (int fr = 0; fr < 2; ++fr)
#pragma unroll
            for (int g = 0; g < 5; ++g) acc[fr][g] = (f32x4){0.f, 0.f, 0.f, 0.f};

#pragma unroll
        for (int q = 0; q < 8; ++q) {
            const int ao = (q >> 2) * 256 + (q & 3) * 32 + l4 * 8;   // ushort offset
            short8v Ah0 = *(const short8v*)(a0 + ao);
            short8v Ah1 = *(const short8v*)(a1 + ao);
            short8v Al0 = *(const short8v*)(a0 + ao + 128);
            short8v Al1 = *(const short8v*)(a1 + ao + 128);
#pragma unroll
            for (int s = 0; s < 4; ++s) {
                const int col = (s < 3) ? s : ((q < 4) ? 3 : 4);
                short8v Bh = *(const short8v*)(Bl + (q * 4 + s) * 512 + lane * 8);
                short8v Bw = *(const short8v*)(Bl + ((q + 8) * 4 + s) * 512 + lane * 8);
                acc[0][col] = __builtin_amdgcn_mfma_f32_16x16x32_bf16(Ah0, Bh, acc[0][col], 0, 0, 0);
                acc[1][col] = __builtin_amdgcn_mfma_f32_16x16x32_bf16(Ah1, Bh, acc[1][col], 0, 0, 0);
                acc[0][col] = __builtin_amdgcn_mfma_f32_16x16x32_bf16(Al0, Bh, acc[0][col], 0, 0, 0);
                acc[1][col] = __builtin_amdgcn_mfma_f32_16x16x32_bf16(Al1, Bh, acc[1][col], 0, 0, 0);
                acc[0][col] = __builtin_amdgcn_mfma_f32_16x16x32_bf16(Ah0, Bw, acc[0][col], 0, 0, 0);
                acc[1][col] = __builtin_amdgcn_mfma_f32_16x16x32_bf16(Ah1, Bw, acc[1][col], 0, 0, 0);
            }
        }

#pragma unroll
        for (int fr = 0; fr < 2; ++fr)
#pragma unroll
            for (int v = 0; v < 4; ++v) {
                const int row = row0 + fr * 16 + l4 * 4 + v;
                float iv  = sigf(acc[fr][0][v] + bi_);
                float ov  = sigf(acc[fr][1][v] + bo_);
                float uv  = fmaxf(acc[fr][2][v] + bu_, 0.f);
                float f1v = sigf(acc[fr][3][v] + b1_);
                float f2v = sigf(acc[fr][4][v] + b2_);
                float lC  = Cin[(size_t)(2 * row) * 128 + j];
                float rC  = Cin[(size_t)(2 * row + 1) * 128 + j];
                float cc_ = fmaf(iv, uv, fmaf(f1v, lC, f2v * rC));
                float hh  = ov * fmaxf(cc_, 0.f);
                Cout[(size_t)row * 128 + j] = cc_;
                unsigned short hhi = bf16_rne(hh);
                unsigned short hlo = bf16_rne(hh - bf16_f32(hhi));
                H2out[(size_t)row * 256 + j]       = hhi;
                H2out[(size_t)row * 256 + 128 + j] = hlo;
            }
    }
}

// ---------------------------------------------------------------------------
// Persistent-B leaf kernel (3 gates, K=128, 24 KB slab).
// ---------------------------------------------------------------------------
template<int T>
__global__ __launch_bounds__(512, 4)
void leaf_gp(const ushort_t* __restrict__ E2, const ushort_t* __restrict__ W4,
             const float* __restrict__ bi, const float* __restrict__ bo,
             const float* __restrict__ bu,
             ushort_t* __restrict__ H2out, float* __restrict__ Cout)
{
    __shared__ ushort_t Bl[12288];                     // 24 KB
    const int tid = threadIdx.x, lane = tid & 63, wid = tid >> 6;
    const int l15 = lane & 15, l4 = lane >> 4;
    const int cb = blockIdx.y;
    const ushort_t* slab = W4 + (size_t)cb * 12288;

#pragma unroll
    for (int r = 0; r < 3; ++r)
        glds16(slab + r * 4096 + wid * 512 + lane * 8, Bl + r * 4096 + wid * 512);
    asm volatile("s_waitcnt vmcnt(0)" ::: "memory");
    __syncthreads();

    const int j = cb * 16 + l15;
    const float bi_ = bi[j], bo_ = bo[j], bu_ = bu[j];
    const int rb = blockIdx.x * (256 * T);

#pragma unroll 1
    for (int t = 0; t < T; ++t) {
        const int row0 = rb + (wid * T + t) * 32;
        const ushort_t* a0 = E2 + (size_t)(row0 + l15) * 256;
        const ushort_t* a1 = E2 + (size_t)(row0 + 16 + l15) * 256;

        f32x4 acc[2][3];
#pragma unroll
        for (int fr = 0; fr < 2; ++fr)
#pragma unroll
            for (int g = 0; g < 3; ++g) acc[fr][g] = (f32x4){0.f, 0.f, 0.f, 0.f};

#pragma unroll
        for (int q = 0; q < 4; ++q) {
            const int ao = q * 32 + l4 * 8;
            short8v Ah0 = *(const short8v*)(a0 + ao);
            short8v Ah1 = *(const short8v*)(a1 + ao);
            short8v Al0 = *(const short8v*)(a0 + ao + 128);
            short8v Al1 = *(const short8v*)(a1 + ao + 128);
#pragma unroll
            for (int s = 0; s < 3; ++s) {
                short8v Bh = *(const short8v*)(Bl + (q * 3 + s) * 512 + lane * 8);
                short8v Bw = *(const short8v*)(Bl + ((q + 4) * 3 + s) * 512 + lane * 8);
                acc[0][s] = __builtin_amdgcn_mfma_f32_16x16x32_bf16(Ah0, Bh, acc[0][s], 0, 0, 0);
                acc[1][s] = __builtin_amdgcn_mfma_f32_16x16x32_bf16(Ah1, Bh, acc[1][s], 0, 0, 0);
                acc[0][s] = __builtin_amdgcn_mfma_f32_16x16x32_bf16(Al0, Bh, acc[0][s], 0, 0, 0);
                acc[1][s] = __builtin_amdgcn_mfma_f32_16x16x32_bf16(Al1, Bh, acc[1][s], 0, 0, 0);
                acc[0][s] = __builtin_amdgcn_mfma_f32_16x16x32_bf16(Ah0, Bw, acc[0][s], 0, 0, 0);
                acc[1][s] = __builtin_amdgcn_mfma_f32_16x16x32_bf16(Ah1, Bw, acc[1][s], 0, 0, 0);
            }
        }

#pragma unroll
        for (int fr = 0; fr < 2; ++fr)
#pragma unroll
            for (int v = 0; v < 4; ++v) {
                const int row = row0 + fr * 16 + l4 * 4 + v;
                float iv = sigf(acc[fr][0][v] + bi_);
                float ov = sigf(acc[fr][1][v] + bo_);
                float uv = fmaxf(acc[fr][2][v] + bu_, 0.f);
                float cc_ = iv * uv;
                float hh  = ov * fmaxf(cc_, 0.f);
                Cout[(size_t)row * 128 + j] = cc_;
                unsigned short hhi = bf16_rne(hh);
                unsigned short hlo = bf16_rne(hh - bf16_f32(hhi));
                H2out[(size_t)row * 256 + j]       = hhi;
                H2out[(size_t)row * 256 + 128 + j] = hlo;
            }
    }
}

// ---------------------------------------------------------------------------
// Tiny level (m<=2048): 1 wave per block; grid (ceil(m/16), 8); cb=blockIdx.y.
// Direct global B loads from the packed W4L table.
// ---------------------------------------------------------------------------
__global__ __launch_bounds__(64)
void level_tiny4(const ushort_t* __restrict__ H2in, const float* __restrict__ Cin,
                 const ushort_t* __restrict__ W4,
                 const float* __restrict__ bUi, const float* __restrict__ bUo,
                 const float* __restrict__ bUu, const float* __restrict__ bf1,
                 const float* __restrict__ bf2,
                 ushort_t* __restrict__ H2out, float* __restrict__ Cout, int n)
{
    const int lane = threadIdx.x;
    const int l15 = lane & 15, l4 = lane >> 4;
    const int cb = blockIdx.y;
    const int rb = blockIdx.x * 16;
    const ushort_t* slab = W4 + (size_t)cb * 32768;

    int prow = rb + l15; if (prow > n - 1) prow = n - 1;
    const ushort_t* arow = H2in + (size_t)(2 * prow) * 256;

    f32x4 acc[5];
#pragma unroll
    for (int g = 0; g < 5; ++g) acc[g] = (f32x4){0.f, 0.f, 0.f, 0.f};

#pragma unroll
    for (int q = 0; q < 8; ++q) {
        const int ao = (q >> 2) * 256 + (q & 3) * 32 + l4 * 8;
        short8v Ah = *(const short8v*)(arow + ao);
        short8v Al = *(const short8v*)(arow + ao + 128);
#pragma unroll
        for (int s = 0; s < 4; ++s) {
            const int col = (s < 3) ? s : ((q < 4) ? 3 : 4);
            short8v Bh = *(const short8v*)(slab + (q * 4 + s) * 512 + lane * 8);
            short8v Bw = *(const short8v*)(slab + ((q + 8) * 4 + s) * 512 + lane * 8);
            acc[col] = __builtin_amdgcn_mfma_f32_16x16x32_bf16(Ah, Bh, acc[col], 0, 0, 0);
            acc[col] = __builtin_amdgcn_mfma_f32_16x16x32_bf16(Al, Bh, acc[col], 0, 0, 0);
            acc[col] = __builtin_amdgcn_mfma_f32_16x16x32_bf16(Ah, Bw, acc[col], 0, 0, 0);
        }
    }

    const int j = cb * 16 + l15;
    const float bi_ = bUi[j], bo_ = bUo[j], bu_ = bUu[j], b1_ = bf1[j], b2_ = bf2[j];
#pragma unroll
    for (int v = 0; v < 4; ++v) {
        const int row = rb + l4 * 4 + v;
        if (row < n) {
            float iv  = sigf(acc[0][v] + bi_);
            float ov  = sigf(acc[1][v] + bo_);
            float uv  = fmaxf(acc[2][v] + bu_, 0.f);
            float f1v = sigf(acc[3][v] + b1_);
            float f2v = sigf(acc[4][v] + b2_);
            float lC  = Cin[(size_t)(2 * row) * 128 + j];
            float rC  = Cin[(size_t)(2 * row + 1) * 128 + j];
            float cc_ = fmaf(iv, uv, fmaf(f1v, lC, f2v * rC));
            float hh  = ov * fmaxf(cc_, 0.f);
            Cout[(size_t)row * 128 + j] = cc_;
            unsigned short hhi = bf16_rne(hh);
            unsigned short hlo = bf16_rne(hh - bf16_f32(hhi));
            H2out[(size_t)row * 256 + j]       = hhi;
            H2out[(size_t)row * 256 + 128 + j] = hlo;
        }
    }
}

// ---------------------------------------------------------------------------
// Projection: out[r] = (hi+lo)[r] @ P + bP   (one wave per row)
// ---------------------------------------------------------------------------
__global__ __launch_bounds__(256)
void proj2(const ushort_t* __restrict__ H2, const float* __restrict__ P,
           const float* __restrict__ bP, float* __restrict__ out, int total)
{
    int wid  = blockIdx.x * 4 + (threadIdx.x >> 6);
    int lane = threadIdx.x & 63;
    if (wid >= total) return;
    const unsigned* hr = (const unsigned*)(H2 + (size_t)wid * 256);
    unsigned uh = hr[lane];
    unsigned ul = hr[64 + lane];
    float h0 = bf16_f32((unsigned short)(uh & 0xffffu)) + bf16_f32((unsigned short)(ul & 0xffffu));
    float h1 = bf16_f32((unsigned short)(uh >> 16)) + bf16_f32((unsigned short)(ul >> 16));
    const int k0 = 2 * lane, k1 = 2 * lane + 1;
    float a[NCLS];
#pragma unroll
    for (int c2 = 0; c2 < NCLS; ++c2)
        a[c2] = fmaf(h0, P[k0 * NCLS + c2], h1 * P[k1 * NCLS + c2]);
    for (int off = 32; off; off >>= 1)
#pragma unroll
        for (int c2 = 0; c2 < NCLS; ++c2) a[c2] += __shfl_down(a[c2], off, 64);
    if (lane == 0)
#pragma unroll
        for (int c2 = 0; c2 < NCLS; ++c2) out[(size_t)wid * NCLS + c2] = a[c2] + bP[c2];
}

// ---------------------------------------------------------------------------
// Host launcher
// ws: W4L@0 (512K) | W4F@524288 (192K) | H2@1MiB (67.1M) | CA (33.55M) | CB (16.78M)
// E2 = upper half of H2 (rows 65536..131072): leaf reads E2, writes H2 lower
// half; levels overwrite the E2 region only after the leaf completes.
// ---------------------------------------------------------------------------
extern "C" void kernel_launch(void* const* d_in, const int* in_sizes, int n_in,
                              void* d_out, int out_size, void* d_ws, size_t ws_size,
                              hipStream_t stream)
{
    const int*   words = (const int*)  d_in[0];
    const float* emb   = (const float*)d_in[1];
    const float* Wi  = (const float*)d_in[2];  const float* bi  = (const float*)d_in[3];
    const float* Wo  = (const float*)d_in[4];  const float* bo  = (const float*)d_in[5];
    const float* Wu  = (const float*)d_in[6];  const float* bu  = (const float*)d_in[7];
    const float* Ui  = (const float*)d_in[8];  const float* bUi = (const float*)d_in[9];
    const float* Uo  = (const float*)d_in[10]; const float* bUo = (const float*)d_in[11];
    const float* Uu  = (const float*)d_in[12]; const float* bUu = (const float*)d_in[13];
    const float* Uf1 = (const float*)d_in[14]; const float* bf1 = (const float*)d_in[15];
    const float* Uf2 = (const float*)d_in[16]; const float* bf2 = (const float*)d_in[17];
    const float* P   = (const float*)d_in[18]; const float* bP  = (const float*)d_in[19];
    float* out = (float*)d_out;

    ushort_t* W4L = (ushort_t*)d_ws;
    ushort_t* W4F = (ushort_t*)((char*)d_ws + 524288);
    ushort_t* H2  = (ushort_t*)((char*)d_ws + 1048576);
    float*    CA  = (float*)((char*)d_ws + 68157440);
    float*    CB  = (float*)((char*)d_ws + 101711872);
    ushort_t* E2  = H2 + (size_t)65536 * 256;        // upper half of H2

    prep_level_w4<<<1024, 256, 0, stream>>>(Ui, Uo, Uu, Uf1, Uf2, W4L);
    prep_leaf_w4<<<384, 256, 0, stream>>>(Wi, Wo, Wu, W4F);
    e2_gather<<<32768, 256, 0, stream>>>(words, emb, E2);

    leaf_gp<2><<<dim3(128, 8), 512, 0, stream>>>(E2, W4F, bi, bo, bu, H2, CA);

    const float* cin = CA;
    float*       cot = CB;
    int n_prev = NLEAF;
    int off_prev = 0;
    int off = NLEAF;
    while (n_prev > 1) {
        int m = n_prev >> 1;
        ushort_t* h_in  = H2 + (size_t)off_prev * 256;
        ushort_t* h_out = H2 + (size_t)off * 256;
        if (m >= 32768) {
            level_gp<2><<<dim3(m / 512, 8), 512, 0, stream>>>(
                h_in, cin, W4L, bUi, bUo, bUu, bf1, bf2, h_out, cot);
        } else if (m >= 4096) {
            level_gp<1><<<dim3(m / 256, 8), 512, 0, stream>>>(
                h_in, cin, W4L, bUi, bUo, bUu, bf1, bf2, h_out, cot);
        } else {
            level_tiny4<<<dim3((m + 15) / 16, 8), 64, 0, stream>>>(
                h_in, cin, W4L, bUi, bUo, bUu, bf1, bf2, h_out, cot, m);
        }
        float* tmp = (float*)cin; cin = cot; cot = tmp;
        off_prev = off;
        off += m;
        n_prev = m;
    }

    int total = off;  // 131071
    proj2<<<(total + 3) / 4, 256, 0, stream>>>(H2, P, bP, out, total);
}